// Round 13
// baseline (346.813 us; speedup 1.0000x reference)
//
#include <hip/hip_runtime.h>
#include <cstdint>
#include <cstddef>

#define NUM_USERS 100000
#define NUM_ITEMS 100000
#define NUM_NODES 200000
#define NUM_EDGES 4000000
#define BATCH     4096
#define EMB       64

#define RPB   512          // rows per bucket (bucket = row >> 9)
#define NB    391          // ceil(NUM_NODES / RPB)
#define CAP   11264        // records per bucket region: mean 10230 + ~10 sigma
#define CHUNK 16384        // edges per block in k_part1 (245 blocks, runs ~42 records)
#define PTHREADS 1024
#define EPB   16           // CHUNK / PTHREADS

// record encoding in tmp: (rowoff << 18) | col   (rowoff < 512, col < 262144)

// ---------------- bf16 helpers (round-to-nearest-even) ----------------

__device__ __forceinline__ unsigned short f2bf(float f) {
    unsigned u = __float_as_uint(f);
    u = (u + 0x7FFFu + ((u >> 16) & 1u)) >> 16;
    return (unsigned short)u;
}
__device__ __forceinline__ float bf2f(unsigned short b) {
    return __uint_as_float(((unsigned)b) << 16);
}

// ---------------- Pass 1: partition edges into fixed-capacity row-buckets ----------
// bcur is memset to 0; positions are bucket-relative (bkt*CAP + base + rank).

__global__ void k_part1(const int* __restrict__ erow, const int* __restrict__ ecol,
                        const float* __restrict__ eval_, int* __restrict__ bcur,
                        int2* __restrict__ tmp) {
    __shared__ int hist[NB];
    __shared__ int base[NB];
    int t = threadIdx.x;
    int start = blockIdx.x * CHUNK;
    for (int i = t; i < NB; i += PTHREADS) hist[i] = 0;
    __syncthreads();
    int rows[EPB], ranks[EPB];
#pragma unroll
    for (int k = 0; k < EPB; ++k) {
        int e = start + t + k * PTHREADS;
        if (e < NUM_EDGES) {
            int r = erow[e];
            rows[k]  = r;
            ranks[k] = atomicAdd(&hist[r >> 9], 1);
        } else {
            rows[k] = -1;
        }
    }
    __syncthreads();
    for (int i = t; i < NB; i += PTHREADS) {
        int c = hist[i];
        base[i] = c ? atomicAdd(&bcur[i], c) : 0;
    }
    __syncthreads();
#pragma unroll
    for (int k = 0; k < EPB; ++k) {
        int e = start + t + k * PTHREADS;
        if (rows[k] >= 0) {
            int r   = rows[k];
            int bkt = r >> 9;
            int pos = bkt * CAP + base[bkt] + ranks[k];
            if (pos < (bkt + 1) * CAP)   // overflow clamp (P astronomically small)
                tmp[pos] = make_int2(((r & 511) << 18) | ecol[e], __float_as_int(eval_[e]));
        }
    }
}

// ---------------- Pass 2: per-bucket sort -> FIXED-CAP epack + rowext -------------
// One block per 512-row bucket, 512 threads. Also converts 1/NB of the fp32
// embedding table to bf16 (fused k_cvt) — streams while sorting is LDS-bound.
// rowext[node] = (start, count) of the node's records in epack.

__global__ void k_part2(const int* __restrict__ bcur, const int2* __restrict__ tmp,
                        int2* __restrict__ epack, int2* __restrict__ rowext,
                        const float* __restrict__ uemb, const float* __restrict__ iemb,
                        unsigned short* __restrict__ xb) {
    __shared__ int cnt[RPB];
    __shared__ int sc[RPB];
    __shared__ int loc[RPB];
    int b = blockIdx.x, t = threadIdx.x;

    // ---- fused cvt: this block's slice of the bf16 table ----
    const int TOT8 = (NUM_NODES * EMB) / 8;                  // 1.6M ushort8 units
    const int PER  = (TOT8 + NB - 1) / NB;                   // 4092
    int u0 = b * PER, u1 = min(u0 + PER, TOT8);
    const size_t UELEMS = (size_t)NUM_USERS * EMB;
    for (int u = u0 + t; u < u1; u += 512) {
        size_t off = (size_t)u * 8;
        const float* src = (off < UELEMS) ? (uemb + off) : (iemb + (off - UELEMS));
        float4 f0 = ((const float4*)src)[0];
        float4 f1 = ((const float4*)src)[1];
        ushort4 o0 = make_ushort4(f2bf(f0.x), f2bf(f0.y), f2bf(f0.z), f2bf(f0.w));
        ushort4 o1 = make_ushort4(f2bf(f1.x), f2bf(f1.y), f2bf(f1.z), f2bf(f1.w));
        ((ushort4*)(xb + off))[0] = o0;
        ((ushort4*)(xb + off))[1] = o1;
    }

    // ---- bucket sort ----
    int base_row = b << 9;
    int nrows = min(RPB, NUM_NODES - base_row);
    int s0 = b * CAP;
    int n = min(bcur[b], CAP);
    cnt[t] = 0;
    __syncthreads();
    for (int i = t; i < n; i += 512)
        atomicAdd(&cnt[((unsigned)tmp[s0 + i].x) >> 18], 1);
    __syncthreads();
    int v = cnt[t];
    sc[t] = v;
    __syncthreads();
    for (int off = 1; off < RPB; off <<= 1) {
        int add = (t >= off) ? sc[t - off] : 0;
        __syncthreads();
        sc[t] += add;
        __syncthreads();
    }
    int cur = s0 + sc[t] - v;   // exclusive, bucket-local
    if (t < nrows) rowext[base_row + t] = make_int2(cur, v);
    loc[t] = cur;
    __syncthreads();
    for (int i = t; i < n; i += 512) {
        int2 rec = tmp[s0 + i];
        int pos = atomicAdd(&loc[((unsigned)rec.x) >> 18], 1);
        epack[pos] = make_int2(rec.x & 0x3FFFF, rec.y);
    }
}

// ---------------- SpMM layer 1: h1 = A * x ----------------
// Wave = 1 row. Four 16-lane edge-groups: group g handles edge e+g, lane
// holds dim-quad (lane&15)*4 via one ushort4 (8 B) load -> one wave-level
// VMEM issue covers 4 edges (512 B). Cross-group sum via 2 shfl_xor.

__global__ void k_spmm1(const int2* __restrict__ rowext, const int2* __restrict__ epack,
                        const unsigned short* __restrict__ xb,
                        unsigned short* __restrict__ h1) {
    int wid  = (blockIdx.x * blockDim.x + threadIdx.x) >> 6;
    int lane = threadIdx.x & 63;
    if (wid >= NUM_NODES) return;
    int g = lane >> 4;
    int q = (lane & 15) * 4;
    int2 se = rowext[wid];
    int s = se.x, t = se.x + se.y;
    float a0 = 0.f, a1 = 0.f, a2 = 0.f, a3 = 0.f;
    for (int e = s; e < t; e += 8) {
        int eA = e + g, eB = e + 4 + g;
        int2 pA = epack[eA < t ? eA : s];
        int2 pB = epack[eB < t ? eB : s];
        float vA = (eA < t) ? __int_as_float(pA.y) : 0.f;
        float vB = (eB < t) ? __int_as_float(pB.y) : 0.f;
        ushort4 xA = *(const ushort4*)(xb + (size_t)pA.x * EMB + q);
        ushort4 xB = *(const ushort4*)(xb + (size_t)pB.x * EMB + q);
        a0 = fmaf(vA, bf2f(xA.x), a0); a1 = fmaf(vA, bf2f(xA.y), a1);
        a2 = fmaf(vA, bf2f(xA.z), a2); a3 = fmaf(vA, bf2f(xA.w), a3);
        a0 = fmaf(vB, bf2f(xB.x), a0); a1 = fmaf(vB, bf2f(xB.y), a1);
        a2 = fmaf(vB, bf2f(xB.z), a2); a3 = fmaf(vB, bf2f(xB.w), a3);
    }
    a0 += __shfl_xor(a0, 16, 64); a1 += __shfl_xor(a1, 16, 64);
    a2 += __shfl_xor(a2, 16, 64); a3 += __shfl_xor(a3, 16, 64);
    a0 += __shfl_xor(a0, 32, 64); a1 += __shfl_xor(a1, 32, 64);
    a2 += __shfl_xor(a2, 32, 64); a3 += __shfl_xor(a3, 32, 64);
    if (lane < 16) {
        ushort4 o = make_ushort4(f2bf(a0), f2bf(a1), f2bf(a2), f2bf(a3));
        *(ushort4*)(h1 + (size_t)wid * EMB + q) = o;
    }
}

// ---------------- Fused layer 2 + scoring (same 4-edge-group gather) ----------------

__device__ __forceinline__ const float* node_ptr(int c, const float* __restrict__ uemb,
                                                 const float* __restrict__ iemb) {
    return (c < NUM_USERS) ? (uemb + (size_t)c * EMB)
                           : (iemb + (size_t)(c - NUM_USERS) * EMB);
}

__global__ void k_final(const int* __restrict__ user, const int* __restrict__ pos,
                        const int* __restrict__ neg,
                        const int2* __restrict__ rowext, const int2* __restrict__ epack,
                        const float* __restrict__ uemb, const float* __restrict__ iemb,
                        const unsigned short* __restrict__ h1, float* __restrict__ out) {
    __shared__ float lds[3 * EMB];
    int b    = blockIdx.x;
    int w    = threadIdx.x >> 6;
    int lane = threadIdx.x & 63;
    int g = lane >> 4;
    int q = (lane & 15) * 4;

    int node;
    if (w == 0)      node = user[b];
    else if (w == 1) node = NUM_USERS + pos[b];
    else             node = NUM_USERS + neg[b];

    int2 se = rowext[node];
    int s = se.x, t = se.x + se.y;
    float a0 = 0.f, a1 = 0.f, a2 = 0.f, a3 = 0.f;
    for (int e = s; e < t; e += 8) {
        int eA = e + g, eB = e + 4 + g;
        int2 pA = epack[eA < t ? eA : s];
        int2 pB = epack[eB < t ? eB : s];
        float vA = (eA < t) ? __int_as_float(pA.y) : 0.f;
        float vB = (eB < t) ? __int_as_float(pB.y) : 0.f;
        ushort4 yA = *(const ushort4*)(h1 + (size_t)pA.x * EMB + q);
        ushort4 yB = *(const ushort4*)(h1 + (size_t)pB.x * EMB + q);
        a0 = fmaf(vA, bf2f(yA.x), a0); a1 = fmaf(vA, bf2f(yA.y), a1);
        a2 = fmaf(vA, bf2f(yA.z), a2); a3 = fmaf(vA, bf2f(yA.w), a3);
        a0 = fmaf(vB, bf2f(yB.x), a0); a1 = fmaf(vB, bf2f(yB.y), a1);
        a2 = fmaf(vB, bf2f(yB.z), a2); a3 = fmaf(vB, bf2f(yB.w), a3);
    }
    a0 += __shfl_xor(a0, 16, 64); a1 += __shfl_xor(a1, 16, 64);
    a2 += __shfl_xor(a2, 16, 64); a3 += __shfl_xor(a3, 16, 64);
    a0 += __shfl_xor(a0, 32, 64); a1 += __shfl_xor(a1, 32, 64);
    a2 += __shfl_xor(a2, 32, 64); a3 += __shfl_xor(a3, 32, 64);

    if (lane < 16) {
        const float* xbp = node_ptr(node, uemb, iemb) + q;
        float4  xd = *(const float4*)xbp;
        ushort4 hn = *(const ushort4*)(h1 + (size_t)node * EMB + q);
        a0 = (a0 + xd.x + bf2f(hn.x)) / 3.0f;
        a1 = (a1 + xd.y + bf2f(hn.y)) / 3.0f;
        a2 = (a2 + xd.z + bf2f(hn.z)) / 3.0f;
        a3 = (a3 + xd.w + bf2f(hn.w)) / 3.0f;
        *(float4*)(lds + w * EMB + q) = make_float4(a0, a1, a2, a3);
    }
    __syncthreads();

    if (w < 2) {
        float prod = lds[lane] * lds[(w + 1) * EMB + lane];
        for (int off = 32; off; off >>= 1) prod += __shfl_xor(prod, off, 64);
        if (lane == 0) out[w * BATCH + b] = prod;
    }
}

// ---------------- launch ----------------

extern "C" void kernel_launch(void* const* d_in, const int* in_sizes, int n_in,
                              void* d_out, int out_size, void* d_ws, size_t ws_size,
                              hipStream_t stream) {
    const int*   user  = (const int*)d_in[0];
    const int*   pos   = (const int*)d_in[1];
    const int*   neg   = (const int*)d_in[2];
    const int*   erow  = (const int*)d_in[3];
    const int*   ecol  = (const int*)d_in[4];
    const float* eval_ = (const float*)d_in[5];
    const float* uemb  = (const float*)d_in[6];
    const float* iemb  = (const float*)d_in[7];
    float* out = (float*)d_out;

    char* ws = (char*)d_ws;
    // layout (bytes) — tmp ALIASES h1 (tmp dead before spmm1 writes h1, stream-ordered):
    //   xb      : 0          .. 25,600,000   (200000*64 bf16)
    //   h1      : 25,600,000 .. 51,200,000   (bf16)
    //   tmp     : 25,600,000 .. 60,833,792   (391*11264 int2, aliases h1)
    //   rowext  : 60,833,792 .. 62,433,792   (200000 int2)
    //   bcur    : 62,433,792 .. 62,437,888   (391 ints)
    //   epack   : 62,437,888 .. 97,671,680   (391*11264 int2, fixed-CAP regions)
    unsigned short* xb = (unsigned short*)(ws);
    unsigned short* h1 = (unsigned short*)(ws + 25600000);
    int2* tmp     = (int2*)(ws + 25600000);
    int2* rowext  = (int2*)(ws + 60833792);
    int*  bcur    = (int*)(ws + 62433792);
    int2* epack   = (int2*)(ws + 62437888);

    hipMemsetAsync(bcur, 0, NB * sizeof(int), stream);

    k_part1<<<(NUM_EDGES + CHUNK - 1) / CHUNK, PTHREADS, 0, stream>>>(erow, ecol, eval_,
                                                                      bcur, tmp);

    k_part2<<<NB, RPB, 0, stream>>>(bcur, tmp, epack, rowext, uemb, iemb, xb);

    k_spmm1<<<(NUM_NODES * 64 + 255) / 256, 256, 0, stream>>>(rowext, epack, xb, h1);

    k_final<<<BATCH, 192, 0, stream>>>(user, pos, neg, rowext, epack,
                                       uemb, iemb, h1, out);
}

// Round 14
// 346.753 us; speedup vs baseline: 1.0002x; 1.0002x over previous
//
#include <hip/hip_runtime.h>
#include <cstdint>
#include <cstddef>

#define NUM_USERS 100000
#define NUM_ITEMS 100000
#define NUM_NODES 200000
#define NUM_EDGES 4000000
#define BATCH     4096
#define EMB       64

#define RPB   512          // rows per bucket (bucket = row >> 9)
#define NB    391          // ceil(NUM_NODES / RPB)
#define CAP   11264        // records per bucket region: mean 10230 + ~10 sigma
#define CHUNK 16384        // edges per block in k_part1 (245 blocks, runs ~42 records)
#define PTHREADS 1024
#define EPB   16           // CHUNK / PTHREADS

// record encoding in tmp: (rowoff << 18) | col   (rowoff < 512, col < 262144)

// ---------------- bf16 helpers ----------------

__device__ __forceinline__ unsigned short f2bf(float f) {
    unsigned u = __float_as_uint(f);
    u = (u + 0x7FFFu + ((u >> 16) & 1u)) >> 16;
    return (unsigned short)u;
}
__device__ __forceinline__ float bf2f(unsigned short b) {
    return __uint_as_float(((unsigned)b) << 16);
}
// packed pair: low bf16 / high bf16 of a uint
__device__ __forceinline__ float bflo(unsigned u) { return __uint_as_float(u << 16); }
__device__ __forceinline__ float bfhi(unsigned u) { return __uint_as_float(u & 0xFFFF0000u); }
__device__ __forceinline__ unsigned pack2(float a, float b) {
    return (unsigned)f2bf(a) | ((unsigned)f2bf(b) << 16);
}

// ---------------- Pass 1: partition edges into fixed-capacity row-buckets ----------

__global__ void k_part1(const int* __restrict__ erow, const int* __restrict__ ecol,
                        const float* __restrict__ eval_, int* __restrict__ bcur,
                        int2* __restrict__ tmp) {
    __shared__ int hist[NB];
    __shared__ int base[NB];
    int t = threadIdx.x;
    int start = blockIdx.x * CHUNK;
    for (int i = t; i < NB; i += PTHREADS) hist[i] = 0;
    __syncthreads();
    int rows[EPB], ranks[EPB];
#pragma unroll
    for (int k = 0; k < EPB; ++k) {
        int e = start + t + k * PTHREADS;
        if (e < NUM_EDGES) {
            int r = erow[e];
            rows[k]  = r;
            ranks[k] = atomicAdd(&hist[r >> 9], 1);
        } else {
            rows[k] = -1;
        }
    }
    __syncthreads();
    for (int i = t; i < NB; i += PTHREADS) {
        int c = hist[i];
        base[i] = c ? atomicAdd(&bcur[i], c) : 0;
    }
    __syncthreads();
#pragma unroll
    for (int k = 0; k < EPB; ++k) {
        int e = start + t + k * PTHREADS;
        if (rows[k] >= 0) {
            int r   = rows[k];
            int bkt = r >> 9;
            int pos = bkt * CAP + base[bkt] + ranks[k];
            if (pos < (bkt + 1) * CAP)   // overflow clamp
                tmp[pos] = make_int2(((r & 511) << 18) | ecol[e], __float_as_int(eval_[e]));
        }
    }
}

// ---------------- Pass 2: per-bucket sort -> FIXED-CAP epack + rowext -------------
// One block per 512-row bucket, 512 threads. Also converts 1/NB of the fp32
// embedding table to bf16 (fused cvt). rowext[node] = (start, count).

__global__ void k_part2(const int* __restrict__ bcur, const int2* __restrict__ tmp,
                        int2* __restrict__ epack, int2* __restrict__ rowext,
                        const float* __restrict__ uemb, const float* __restrict__ iemb,
                        unsigned short* __restrict__ xb) {
    __shared__ int cnt[RPB];
    __shared__ int sc[RPB];
    __shared__ int loc[RPB];
    int b = blockIdx.x, t = threadIdx.x;

    const int TOT8 = (NUM_NODES * EMB) / 8;                  // 1.6M ushort8 units
    const int PER  = (TOT8 + NB - 1) / NB;                   // 4092
    int u0 = b * PER, u1 = min(u0 + PER, TOT8);
    const size_t UELEMS = (size_t)NUM_USERS * EMB;
    for (int u = u0 + t; u < u1; u += 512) {
        size_t off = (size_t)u * 8;
        const float* src = (off < UELEMS) ? (uemb + off) : (iemb + (off - UELEMS));
        float4 f0 = ((const float4*)src)[0];
        float4 f1 = ((const float4*)src)[1];
        ushort4 o0 = make_ushort4(f2bf(f0.x), f2bf(f0.y), f2bf(f0.z), f2bf(f0.w));
        ushort4 o1 = make_ushort4(f2bf(f1.x), f2bf(f1.y), f2bf(f1.z), f2bf(f1.w));
        ((ushort4*)(xb + off))[0] = o0;
        ((ushort4*)(xb + off))[1] = o1;
    }

    int base_row = b << 9;
    int nrows = min(RPB, NUM_NODES - base_row);
    int s0 = b * CAP;
    int n = min(bcur[b], CAP);
    cnt[t] = 0;
    __syncthreads();
    for (int i = t; i < n; i += 512)
        atomicAdd(&cnt[((unsigned)tmp[s0 + i].x) >> 18], 1);
    __syncthreads();
    int v = cnt[t];
    sc[t] = v;
    __syncthreads();
    for (int off = 1; off < RPB; off <<= 1) {
        int add = (t >= off) ? sc[t - off] : 0;
        __syncthreads();
        sc[t] += add;
        __syncthreads();
    }
    int cur = s0 + sc[t] - v;   // exclusive, bucket-local
    if (t < nrows) rowext[base_row + t] = make_int2(cur, v);
    loc[t] = cur;
    __syncthreads();
    for (int i = t; i < n; i += 512) {
        int2 rec = tmp[s0 + i];
        int pos = atomicAdd(&loc[((unsigned)rec.x) >> 18], 1);
        epack[pos] = make_int2(rec.x & 0x3FFFF, rec.y);
    }
}

// ---------------- SpMM layer 1: h1 = A * x ----------------
// Wave = 1 row. EIGHT 8-lane edge-groups: group g (lane>>3) handles edge e+g,
// lane holds dim-octet (lane&7)*8 via ONE uint4 (16 B) load -> one wave-level
// VMEM issue covers 8 edges (1 KB). Halves VMEM issue count vs ushort4 variant.
// Cross-group sum via 3 shfl_xor (8,16,32); lanes 0..7 store the 128 B row.

__global__ void k_spmm1(const int2* __restrict__ rowext, const int2* __restrict__ epack,
                        const unsigned short* __restrict__ xb,
                        unsigned short* __restrict__ h1) {
    int wid  = (blockIdx.x * blockDim.x + threadIdx.x) >> 6;
    int lane = threadIdx.x & 63;
    if (wid >= NUM_NODES) return;
    int g = lane >> 3;
    int q = (lane & 7) * 8;
    int2 se = rowext[wid];
    int s = se.x, t = se.x + se.y;
    float a0 = 0.f, a1 = 0.f, a2 = 0.f, a3 = 0.f;
    float a4 = 0.f, a5 = 0.f, a6 = 0.f, a7 = 0.f;
    for (int e = s; e < t; e += 8) {
        int idx = e + g;
        int2 p = epack[idx < t ? idx : s];
        float v = (idx < t) ? __int_as_float(p.y) : 0.f;
        uint4 X = *(const uint4*)(xb + (size_t)p.x * EMB + q);
        a0 = fmaf(v, bflo(X.x), a0); a1 = fmaf(v, bfhi(X.x), a1);
        a2 = fmaf(v, bflo(X.y), a2); a3 = fmaf(v, bfhi(X.y), a3);
        a4 = fmaf(v, bflo(X.z), a4); a5 = fmaf(v, bfhi(X.z), a5);
        a6 = fmaf(v, bflo(X.w), a6); a7 = fmaf(v, bfhi(X.w), a7);
    }
#pragma unroll
    for (int off = 8; off < 64; off <<= 1) {
        a0 += __shfl_xor(a0, off, 64); a1 += __shfl_xor(a1, off, 64);
        a2 += __shfl_xor(a2, off, 64); a3 += __shfl_xor(a3, off, 64);
        a4 += __shfl_xor(a4, off, 64); a5 += __shfl_xor(a5, off, 64);
        a6 += __shfl_xor(a6, off, 64); a7 += __shfl_xor(a7, off, 64);
    }
    if (lane < 8) {
        uint4 o = make_uint4(pack2(a0, a1), pack2(a2, a3), pack2(a4, a5), pack2(a6, a7));
        *(uint4*)(h1 + (size_t)wid * EMB + q) = o;
    }
}

// ---------------- Fused layer 2 + scoring (same 8-edge-group gather) ----------------

__device__ __forceinline__ const float* node_ptr(int c, const float* __restrict__ uemb,
                                                 const float* __restrict__ iemb) {
    return (c < NUM_USERS) ? (uemb + (size_t)c * EMB)
                           : (iemb + (size_t)(c - NUM_USERS) * EMB);
}

__global__ void k_final(const int* __restrict__ user, const int* __restrict__ pos,
                        const int* __restrict__ neg,
                        const int2* __restrict__ rowext, const int2* __restrict__ epack,
                        const float* __restrict__ uemb, const float* __restrict__ iemb,
                        const unsigned short* __restrict__ h1, float* __restrict__ out) {
    __shared__ float lds[3 * EMB];
    int b    = blockIdx.x;
    int w    = threadIdx.x >> 6;
    int lane = threadIdx.x & 63;
    int g = lane >> 3;
    int q = (lane & 7) * 8;

    int node;
    if (w == 0)      node = user[b];
    else if (w == 1) node = NUM_USERS + pos[b];
    else             node = NUM_USERS + neg[b];

    int2 se = rowext[node];
    int s = se.x, t = se.x + se.y;
    float a0 = 0.f, a1 = 0.f, a2 = 0.f, a3 = 0.f;
    float a4 = 0.f, a5 = 0.f, a6 = 0.f, a7 = 0.f;
    for (int e = s; e < t; e += 8) {
        int idx = e + g;
        int2 p = epack[idx < t ? idx : s];
        float v = (idx < t) ? __int_as_float(p.y) : 0.f;
        uint4 Y = *(const uint4*)(h1 + (size_t)p.x * EMB + q);
        a0 = fmaf(v, bflo(Y.x), a0); a1 = fmaf(v, bfhi(Y.x), a1);
        a2 = fmaf(v, bflo(Y.y), a2); a3 = fmaf(v, bfhi(Y.y), a3);
        a4 = fmaf(v, bflo(Y.z), a4); a5 = fmaf(v, bfhi(Y.z), a5);
        a6 = fmaf(v, bflo(Y.w), a6); a7 = fmaf(v, bfhi(Y.w), a7);
    }
#pragma unroll
    for (int off = 8; off < 64; off <<= 1) {
        a0 += __shfl_xor(a0, off, 64); a1 += __shfl_xor(a1, off, 64);
        a2 += __shfl_xor(a2, off, 64); a3 += __shfl_xor(a3, off, 64);
        a4 += __shfl_xor(a4, off, 64); a5 += __shfl_xor(a5, off, 64);
        a6 += __shfl_xor(a6, off, 64); a7 += __shfl_xor(a7, off, 64);
    }

    if (lane < 8) {
        const float* xbp = node_ptr(node, uemb, iemb) + q;
        float4 xd0 = ((const float4*)xbp)[0];
        float4 xd1 = ((const float4*)xbp)[1];
        uint4  hn  = *(const uint4*)(h1 + (size_t)node * EMB + q);
        a0 = (a0 + xd0.x + bflo(hn.x)) / 3.0f;
        a1 = (a1 + xd0.y + bfhi(hn.x)) / 3.0f;
        a2 = (a2 + xd0.z + bflo(hn.y)) / 3.0f;
        a3 = (a3 + xd0.w + bfhi(hn.y)) / 3.0f;
        a4 = (a4 + xd1.x + bflo(hn.z)) / 3.0f;
        a5 = (a5 + xd1.y + bfhi(hn.z)) / 3.0f;
        a6 = (a6 + xd1.z + bflo(hn.w)) / 3.0f;
        a7 = (a7 + xd1.w + bfhi(hn.w)) / 3.0f;
        float* dst = lds + w * EMB + q;
        dst[0] = a0; dst[1] = a1; dst[2] = a2; dst[3] = a3;
        dst[4] = a4; dst[5] = a5; dst[6] = a6; dst[7] = a7;
    }
    __syncthreads();

    if (w < 2) {
        float prod = lds[lane] * lds[(w + 1) * EMB + lane];
        for (int off = 32; off; off >>= 1) prod += __shfl_xor(prod, off, 64);
        if (lane == 0) out[w * BATCH + b] = prod;
    }
}

// ---------------- launch ----------------

extern "C" void kernel_launch(void* const* d_in, const int* in_sizes, int n_in,
                              void* d_out, int out_size, void* d_ws, size_t ws_size,
                              hipStream_t stream) {
    const int*   user  = (const int*)d_in[0];
    const int*   pos   = (const int*)d_in[1];
    const int*   neg   = (const int*)d_in[2];
    const int*   erow  = (const int*)d_in[3];
    const int*   ecol  = (const int*)d_in[4];
    const float* eval_ = (const float*)d_in[5];
    const float* uemb  = (const float*)d_in[6];
    const float* iemb  = (const float*)d_in[7];
    float* out = (float*)d_out;

    char* ws = (char*)d_ws;
    // layout (bytes) — tmp ALIASES h1 (tmp dead before spmm1 writes h1, stream-ordered):
    //   xb      : 0          .. 25,600,000   (200000*64 bf16)
    //   h1      : 25,600,000 .. 51,200,000   (bf16)
    //   tmp     : 25,600,000 .. 60,833,792   (391*11264 int2, aliases h1)
    //   rowext  : 60,833,792 .. 62,433,792   (200000 int2)
    //   bcur    : 62,433,792 .. 62,437,888   (391 ints)
    //   epack   : 62,437,888 .. 97,671,680   (391*11264 int2, fixed-CAP regions)
    unsigned short* xb = (unsigned short*)(ws);
    unsigned short* h1 = (unsigned short*)(ws + 25600000);
    int2* tmp     = (int2*)(ws + 25600000);
    int2* rowext  = (int2*)(ws + 60833792);
    int*  bcur    = (int*)(ws + 62433792);
    int2* epack   = (int2*)(ws + 62437888);

    hipMemsetAsync(bcur, 0, NB * sizeof(int), stream);

    k_part1<<<(NUM_EDGES + CHUNK - 1) / CHUNK, PTHREADS, 0, stream>>>(erow, ecol, eval_,
                                                                      bcur, tmp);

    k_part2<<<NB, RPB, 0, stream>>>(bcur, tmp, epack, rowext, uemb, iemb, xb);

    k_spmm1<<<(NUM_NODES * 64 + 255) / 256, 256, 0, stream>>>(rowext, epack, xb, h1);

    k_final<<<BATCH, 192, 0, stream>>>(user, pos, neg, rowext, epack,
                                       uemb, iemb, h1, out);
}